// Round 1
// baseline (1653.505 us; speedup 1.0000x reference)
//
#include <hip/hip_runtime.h>

#define B_TOT   4096
#define T_STEPS 512
#define IN_F    5
#define D_FC    32
#define D_H     64
#define KTOT    96      // D_FC + D_H
#define NWAVES  4
#define WB      4       // batches per block (one per wave for elementwise)
#define KPW     24      // KTOT / NWAVES

// 2^x via hardware exp
__device__ __forceinline__ float fexp2(float x) { return __builtin_amdgcn_exp2f(x); }
// precise sigmoid/tanh (precise division; only exp2 is approx ~1ulp)
__device__ __forceinline__ float fsig(float x) {
    return 1.0f / (1.0f + fexp2(-1.4426950408889634f * x));
}
__device__ __forceinline__ float ftanh(float x) {
    float e = fexp2(2.8853900817779268f * x);   // exp(2x)
    return 1.0f - 2.0f / (e + 1.0f);            // saturates correctly at +-inf
}

__global__ __launch_bounds__(256) void lstm_kernel(
    const float* __restrict__ x,
    const float* __restrict__ W0,
    const float* __restrict__ b0,
    const float* __restrict__ W_ih,
    const float* __restrict__ W_hh,
    const float* __restrict__ b_ih,
    const float* __restrict__ b_hh,
    const float* __restrict__ Wo,
    const float* __restrict__ bo,
    float* __restrict__ out)
{
    // lds_h[b][0..31] = h0(t), lds_h[b][32..95] = h(t-1)
    __shared__ __align__(16) float lds_h[WB][KTOT];
    // partial gate sums: [k-split wave][batch][reordered gate 4j+q]
    __shared__ __align__(16) float pg[NWAVES][WB][4 * D_H];

    const int tid  = threadIdx.x;
    const int lane = tid & 63;
    const int w    = tid >> 6;                 // wave id = k-split id = owned batch
    const int bblk = blockIdx.x * WB;          // global batch base

    // ---- weights into registers: 4 gate rows (q*64+lane) x 24 cols ----
    float Wreg[4][KPW];
    #pragma unroll
    for (int q = 0; q < 4; ++q) {
        const int row = q * 64 + lane;
        #pragma unroll
        for (int kk = 0; kk < KPW; ++kk) {
            const int col = w * KPW + kk;
            Wreg[q][kk] = (col < D_FC) ? W_ih[row * D_FC + col]
                                       : W_hh[row * D_H + (col - D_FC)];
        }
    }

    float bias[4];
    #pragma unroll
    for (int q = 0; q < 4; ++q)
        bias[q] = b_ih[q * 64 + lane] + b_hh[q * 64 + lane];

    // fc0 row weights for lanes < 32
    float w0r[IN_F];
    float b0r = 0.0f;
    #pragma unroll
    for (int i = 0; i < IN_F; ++i) w0r[i] = 0.0f;
    if (lane < D_FC) {
        #pragma unroll
        for (int i = 0; i < IN_F; ++i) w0r[i] = W0[lane * IN_F + i];
        b0r = b0[lane];
    }

    const float wo_lane = Wo[lane];
    const float bo_s    = bo[0];

    // zero initial hidden state region
    lds_h[w][D_FC + lane] = 0.0f;

    // prefetch x(t=0) for my wave's batch
    const float* xb = x + (size_t)(bblk + w) * T_STEPS * IN_F;
    float xr[IN_F];
    #pragma unroll
    for (int i = 0; i < IN_F; ++i) xr[i] = 0.0f;
    if (lane < D_FC) {
        #pragma unroll
        for (int i = 0; i < IN_F; ++i) xr[i] = xb[i];
    }

    float c_state = 0.0f;
    float h_new   = 0.0f;

    for (int t = 0; t < T_STEPS; ++t) {
        // --- fc0 for batch w using prefetched x, then prefetch next x ---
        if (lane < D_FC) {
            float h0 = b0r;
            #pragma unroll
            for (int i = 0; i < IN_F; ++i) h0 = fmaf(w0r[i], xr[i], h0);
            lds_h[w][lane] = h0;
        }
        {
            const int tn = (t + 1 < T_STEPS) ? (t + 1) : (T_STEPS - 1);
            const float* xp = xb + tn * IN_F;
            if (lane < D_FC) {
                #pragma unroll
                for (int i = 0; i < IN_F; ++i) xr[i] = xp[i];
            }
        }
        __syncthreads();   // A: h0 visible; prev step's pg reads finished

        // --- partial gates over this wave's k-slice for all WB batches ---
        float acc[4][WB];
        #pragma unroll
        for (int q = 0; q < 4; ++q)
            #pragma unroll
            for (int b = 0; b < WB; ++b) acc[q][b] = 0.0f;

        #pragma unroll
        for (int kc = 0; kc < KPW / 4; ++kc) {
            float4 hv[WB];
            #pragma unroll
            for (int b = 0; b < WB; ++b)
                hv[b] = *(const float4*)&lds_h[b][w * KPW + kc * 4]; // broadcast
            #pragma unroll
            for (int b = 0; b < WB; ++b) {
                #pragma unroll
                for (int q = 0; q < 4; ++q) {
                    acc[q][b] = fmaf(Wreg[q][4 * kc + 0], hv[b].x, acc[q][b]);
                    acc[q][b] = fmaf(Wreg[q][4 * kc + 1], hv[b].y, acc[q][b]);
                    acc[q][b] = fmaf(Wreg[q][4 * kc + 2], hv[b].z, acc[q][b]);
                    acc[q][b] = fmaf(Wreg[q][4 * kc + 3], hv[b].w, acc[q][b]);
                }
            }
        }

        // --- write partials (contiguous 1KB per instr, conflict-free) ---
        #pragma unroll
        for (int b = 0; b < WB; ++b) {
            float4 v = make_float4(acc[0][b], acc[1][b], acc[2][b], acc[3][b]);
            *(float4*)&pg[w][b][4 * lane] = v;
        }
        __syncthreads();   // B

        // --- reduce partials for owned batch (b = w) + LSTM elementwise ---
        float4 g0 = *(const float4*)&pg[0][w][4 * lane];
        float4 g1 = *(const float4*)&pg[1][w][4 * lane];
        float4 g2 = *(const float4*)&pg[2][w][4 * lane];
        float4 g3 = *(const float4*)&pg[3][w][4 * lane];
        float gi = g0.x + g1.x + g2.x + g3.x + bias[0];
        float gf = g0.y + g1.y + g2.y + g3.y + bias[1];
        float gg = g0.z + g1.z + g2.z + g3.z + bias[2];
        float go = g0.w + g1.w + g2.w + g3.w + bias[3];

        float ig = fsig(gi);
        float fg = fsig(gf);
        float g_ = ftanh(gg);
        float og = fsig(go);
        c_state = fmaf(fg, c_state, ig * g_);
        h_new   = og * ftanh(c_state);
        lds_h[w][D_FC + lane] = h_new;
        // next iteration's barrier A makes h(t) visible before it is read
    }

    // --- output head: out[b] = bo + sum_j h_last[j] * Wo[j] ---
    float v = h_new * wo_lane;
    #pragma unroll
    for (int off = 32; off >= 1; off >>= 1)
        v += __shfl_xor(v, off, 64);
    if (lane == 0)
        out[bblk + w] = v + bo_s;
}

extern "C" void kernel_launch(void* const* d_in, const int* in_sizes, int n_in,
                              void* d_out, int out_size, void* d_ws, size_t ws_size,
                              hipStream_t stream) {
    const float* x    = (const float*)d_in[0];
    const float* W0   = (const float*)d_in[1];
    const float* b0   = (const float*)d_in[2];
    const float* W_ih = (const float*)d_in[3];
    const float* W_hh = (const float*)d_in[4];
    const float* b_ih = (const float*)d_in[5];
    const float* b_hh = (const float*)d_in[6];
    const float* Wo   = (const float*)d_in[7];
    const float* bo   = (const float*)d_in[8];
    float* out = (float*)d_out;

    hipLaunchKernelGGL(lstm_kernel, dim3(B_TOT / WB), dim3(NWAVES * 64), 0, stream,
                       x, W0, b0, W_ih, W_hh, b_ih, b_hh, Wo, bo, out);
}

// Round 2
// 1644.372 us; speedup vs baseline: 1.0056x; 1.0056x over previous
//
#include <hip/hip_runtime.h>

#define B_TOT   4096
#define T_STEPS 512
#define IN_F    5
#define D_FC    32
#define D_H     64
#define KTOT    96      // D_FC + D_H
#define NWAVES  4
#define WB      4       // batches per block (one per wave for elementwise)
#define KPW     24      // KTOT / NWAVES (even, so k-pairs never straddle the 32 boundary)

typedef float v2f __attribute__((ext_vector_type(2)));

__device__ __forceinline__ float fexp2(float x) { return __builtin_amdgcn_exp2f(x); }
__device__ __forceinline__ float frcp(float x)  { return __builtin_amdgcn_rcpf(x); }

// fast sigmoid/tanh: v_rcp_f32 is ~1 ulp; absmax headroom is ~2.7e-3, measured 0.0 with precise div
__device__ __forceinline__ float fsig(float x) {
    return frcp(1.0f + fexp2(-1.4426950408889634f * x));
}
__device__ __forceinline__ float ftanh(float x) {
    float e = fexp2(2.8853900817779268f * x);   // exp(2x); saturates correctly at +-inf
    return 1.0f - 2.0f * frcp(e + 1.0f);
}

// packed fp32 FMA: acc(lo,hi) += w(lo,hi) * h(lo,hi). Forces arch-VGPR operands
// (no AGPR round-trip) and halves FMA instruction count.
__device__ __forceinline__ void pk_fma(v2f& acc, v2f w, v2f h) {
    asm("v_pk_fma_f32 %0, %1, %2, %0" : "+v"(acc) : "v"(w), "v"(h));
}

__global__ __launch_bounds__(256) void lstm_kernel(
    const float* __restrict__ x,
    const float* __restrict__ W0,
    const float* __restrict__ b0,
    const float* __restrict__ W_ih,
    const float* __restrict__ W_hh,
    const float* __restrict__ b_ih,
    const float* __restrict__ b_hh,
    const float* __restrict__ Wo,
    const float* __restrict__ bo,
    float* __restrict__ out)
{
    // lds_h[b][0..31] = h0(t), lds_h[b][32..95] = h(t-1)
    __shared__ __align__(16) float lds_h[WB][KTOT];
    // partial gate sums: [k-split wave][batch][reordered gate 4j+q]
    __shared__ __align__(16) float pg[NWAVES][WB][4 * D_H];

    const int tid  = threadIdx.x;
    const int lane = tid & 63;
    const int w    = tid >> 6;                 // wave id = k-split id = owned batch
    const int bblk = blockIdx.x * WB;          // global batch base

    // ---- weights into registers as k-pairs: 4 gate rows (q*64+lane) x 12 v2f pairs ----
    v2f Wreg[4][KPW / 2];
    #pragma unroll
    for (int q = 0; q < 4; ++q) {
        const int row = q * 64 + lane;
        #pragma unroll
        for (int p = 0; p < KPW / 2; ++p) {
            const int c0 = w * KPW + 2 * p;
            const int c1 = c0 + 1;
            float w0v = (c0 < D_FC) ? W_ih[row * D_FC + c0] : W_hh[row * D_H + (c0 - D_FC)];
            float w1v = (c1 < D_FC) ? W_ih[row * D_FC + c1] : W_hh[row * D_H + (c1 - D_FC)];
            v2f t; t.x = w0v; t.y = w1v;
            Wreg[q][p] = t;
        }
    }

    float bias[4];
    #pragma unroll
    for (int q = 0; q < 4; ++q)
        bias[q] = b_ih[q * 64 + lane] + b_hh[q * 64 + lane];

    // fc0 row weights for lanes < 32
    float w0r[IN_F];
    float b0r = 0.0f;
    #pragma unroll
    for (int i = 0; i < IN_F; ++i) w0r[i] = 0.0f;
    if (lane < D_FC) {
        #pragma unroll
        for (int i = 0; i < IN_F; ++i) w0r[i] = W0[lane * IN_F + i];
        b0r = b0[lane];
    }

    const float wo_lane = Wo[lane];
    const float bo_s    = bo[0];

    // zero initial hidden state region
    lds_h[w][D_FC + lane] = 0.0f;

    // prefetch x(t=0) for my wave's batch
    const float* xb = x + (size_t)(bblk + w) * T_STEPS * IN_F;
    float xr[IN_F];
    #pragma unroll
    for (int i = 0; i < IN_F; ++i) xr[i] = 0.0f;
    if (lane < D_FC) {
        #pragma unroll
        for (int i = 0; i < IN_F; ++i) xr[i] = xb[i];
    }

    float c_state = 0.0f;
    float h_new   = 0.0f;

    for (int t = 0; t < T_STEPS; ++t) {
        // --- fc0 for batch w using prefetched x, then prefetch next x ---
        if (lane < D_FC) {
            float h0 = b0r;
            #pragma unroll
            for (int i = 0; i < IN_F; ++i) h0 = fmaf(w0r[i], xr[i], h0);
            lds_h[w][lane] = h0;
        }
        {
            const int tn = (t + 1 < T_STEPS) ? (t + 1) : (T_STEPS - 1);
            const float* xp = xb + tn * IN_F;
            if (lane < D_FC) {
                #pragma unroll
                for (int i = 0; i < IN_F; ++i) xr[i] = xp[i];
            }
        }
        __syncthreads();   // A: h0 visible; prev step's pg reads finished

        // --- partial gates over this wave's k-slice for all WB batches ---
        // acc lo = even-k partial, hi = odd-k partial; summed at pg-write
        v2f acc[4][WB];
        #pragma unroll
        for (int q = 0; q < 4; ++q)
            #pragma unroll
            for (int b = 0; b < WB; ++b) { acc[q][b].x = 0.0f; acc[q][b].y = 0.0f; }

        #pragma unroll
        for (int kc = 0; kc < KPW / 4; ++kc) {
            #pragma unroll
            for (int b = 0; b < WB; ++b) {
                float4 h4 = *(const float4*)&lds_h[b][w * KPW + kc * 4]; // broadcast read
                v2f h01; h01.x = h4.x; h01.y = h4.y;
                v2f h23; h23.x = h4.z; h23.y = h4.w;
                #pragma unroll
                for (int q = 0; q < 4; ++q) {
                    pk_fma(acc[q][b], Wreg[q][2 * kc + 0], h01);
                    pk_fma(acc[q][b], Wreg[q][2 * kc + 1], h23);
                }
            }
        }

        // --- write partials (contiguous 1KB per instr, conflict-free) ---
        #pragma unroll
        for (int b = 0; b < WB; ++b) {
            float4 v = make_float4(acc[0][b].x + acc[0][b].y,
                                   acc[1][b].x + acc[1][b].y,
                                   acc[2][b].x + acc[2][b].y,
                                   acc[3][b].x + acc[3][b].y);
            *(float4*)&pg[w][b][4 * lane] = v;
        }
        __syncthreads();   // B

        // --- reduce partials for owned batch (b = w) + LSTM elementwise ---
        float4 g0 = *(const float4*)&pg[0][w][4 * lane];
        float4 g1 = *(const float4*)&pg[1][w][4 * lane];
        float4 g2 = *(const float4*)&pg[2][w][4 * lane];
        float4 g3 = *(const float4*)&pg[3][w][4 * lane];
        float gi = g0.x + g1.x + g2.x + g3.x + bias[0];
        float gf = g0.y + g1.y + g2.y + g3.y + bias[1];
        float gg = g0.z + g1.z + g2.z + g3.z + bias[2];
        float go = g0.w + g1.w + g2.w + g3.w + bias[3];

        float ig = fsig(gi);
        float fg = fsig(gf);
        float g_ = ftanh(gg);
        float og = fsig(go);
        c_state = fmaf(fg, c_state, ig * g_);
        h_new   = og * ftanh(c_state);
        lds_h[w][D_FC + lane] = h_new;
        // next iteration's barrier A makes h(t) visible before it is read
    }

    // --- output head: out[b] = bo + sum_j h_last[j] * Wo[j] ---
    float v = h_new * wo_lane;
    #pragma unroll
    for (int off = 32; off >= 1; off >>= 1)
        v += __shfl_xor(v, off, 64);
    if (lane == 0)
        out[bblk + w] = v + bo_s;
}

extern "C" void kernel_launch(void* const* d_in, const int* in_sizes, int n_in,
                              void* d_out, int out_size, void* d_ws, size_t ws_size,
                              hipStream_t stream) {
    const float* x    = (const float*)d_in[0];
    const float* W0   = (const float*)d_in[1];
    const float* b0   = (const float*)d_in[2];
    const float* W_ih = (const float*)d_in[3];
    const float* W_hh = (const float*)d_in[4];
    const float* b_ih = (const float*)d_in[5];
    const float* b_hh = (const float*)d_in[6];
    const float* Wo   = (const float*)d_in[7];
    const float* bo   = (const float*)d_in[8];
    float* out = (float*)d_out;

    hipLaunchKernelGGL(lstm_kernel, dim3(B_TOT / WB), dim3(NWAVES * 64), 0, stream,
                       x, W0, b0, W_ih, W_hh, b_ih, b_hh, Wo, bo, out);
}

// Round 3
// 355.689 us; speedup vs baseline: 4.6487x; 4.6231x over previous
//
#include <hip/hip_runtime.h>

#define B_TOT   4096
#define T_STEPS 512
#define IN_F    5
#define D_FC    32
#define D_H     64
#define MB      16      // batches per block = one MFMA M-tile
#define ROWPAD  104     // f16 elems per Hcat row (96 + 8 pad: 208B, 16B-aligned, bank-spread)

typedef _Float16 h8 __attribute__((ext_vector_type(8)));
typedef _Float16 h2 __attribute__((ext_vector_type(2)));
typedef float    f4 __attribute__((ext_vector_type(4)));

__device__ __forceinline__ float fexp2(float x) { return __builtin_amdgcn_exp2f(x); }
__device__ __forceinline__ float frcp(float x)  { return __builtin_amdgcn_rcpf(x); }
__device__ __forceinline__ float fsig(float x) {
    return frcp(1.0f + fexp2(-1.4426950408889634f * x));
}
__device__ __forceinline__ float ftanh(float x) {
    float e = fexp2(2.8853900817779268f * x);   // exp(2x); saturates at +-inf
    return 1.0f - 2.0f * frcp(e + 1.0f);
}

__global__ __launch_bounds__(256) void lstm_mfma(
    const float* __restrict__ x,
    const float* __restrict__ W0,
    const float* __restrict__ b0,
    const float* __restrict__ W_ih,
    const float* __restrict__ W_hh,
    const float* __restrict__ b_ih,
    const float* __restrict__ b_hh,
    const float* __restrict__ Wo,
    const float* __restrict__ bo,
    float* __restrict__ out)
{
    // Hcat[b][0..31] = h0(t) (fc0 output), Hcat[b][32..95] = h(t-1), f16
    __shared__ _Float16 Hcat[MB][ROWPAD];

    const int tid  = threadIdx.x;
    const int lane = tid & 63;
    const int w    = tid >> 6;      // wave id: owns hidden dims j in [w*16, w*16+16)
    const int col  = lane & 15;     // MFMA n-index / m-index
    const int quad = lane >> 4;     // MFMA k-group / row-group
    const int bblk = blockIdx.x * MB;

    // ---- preload weights as B-fragments (resident for the whole kernel) ----
    // Tile q covers gate-columns {q*64 + w*16 + col}: lane holds gate q for
    // hidden j = w*16+col across K. B[k=quad*8+jj][n] = W[row n][k].
    h8 Bf[4][3];
    #pragma unroll
    for (int q = 0; q < 4; ++q) {
        const int row = q * 64 + w * 16 + col;
        #pragma unroll
        for (int c = 0; c < 3; ++c) {
            h8 f;
            #pragma unroll
            for (int jj = 0; jj < 8; ++jj) {
                const int k = c * 32 + quad * 8 + jj;
                const float wv = (k < D_FC) ? W_ih[row * D_FC + k]
                                            : W_hh[row * D_H + (k - D_FC)];
                f[jj] = (_Float16)wv;
            }
            Bf[q][c] = f;
        }
    }

    float bias_q[4];
    #pragma unroll
    for (int q = 0; q < 4; ++q) {
        const int row = q * 64 + w * 16 + col;
        bias_q[q] = b_ih[row] + b_hh[row];
    }

    // ---- fc0 assignment: thread -> (batch fb, col pair 2*fp, 2*fp+1) ----
    const int fb = tid >> 4;
    const int fp = tid & 15;
    float w0c[2][IN_F], b0c[2];
    #pragma unroll
    for (int u = 0; u < 2; ++u) {
        const int cc = 2 * fp + u;
        #pragma unroll
        for (int i = 0; i < IN_F; ++i) w0c[u][i] = W0[cc * IN_F + i];
        b0c[u] = b0[cc];
    }

    const float* xb = x + (size_t)(bblk + fb) * T_STEPS * IN_F;

    // zero initial hidden region
    #pragma unroll
    for (int kk = 0; kk < 4; ++kk)
        Hcat[fb][D_FC + fp + 16 * kk] = (_Float16)0.0f;

    // fc0 for t=0
    {
        float xr0[IN_F];
        #pragma unroll
        for (int i = 0; i < IN_F; ++i) xr0[i] = xb[i];
        float a = b0c[0], b = b0c[1];
        #pragma unroll
        for (int i = 0; i < IN_F; ++i) {
            a = fmaf(w0c[0][i], xr0[i], a);
            b = fmaf(w0c[1][i], xr0[i], b);
        }
        h2 p; p.x = (_Float16)a; p.y = (_Float16)b;
        *(h2*)&Hcat[fb][2 * fp] = p;
    }
    // prefetch x(t=1)
    float xr[IN_F];
    #pragma unroll
    for (int i = 0; i < IN_F; ++i) xr[i] = xb[IN_F + i];

    // cell state: lane holds c for hidden j=w*16+col, batches quad*4+r
    float c_st[4] = {0.0f, 0.0f, 0.0f, 0.0f};

    __syncthreads();

    for (int t = 0; t < T_STEPS; ++t) {
        // A-fragments: A[m=col][k=quad*8+jj] from Hcat (16B-aligned b128 reads)
        const h8 A0 = *(const h8*)&Hcat[col][quad * 8];
        const h8 A1 = *(const h8*)&Hcat[col][32 + quad * 8];
        const h8 A2 = *(const h8*)&Hcat[col][64 + quad * 8];

        f4 acc[4];
        #pragma unroll
        for (int q = 0; q < 4; ++q) {
            f4 a = { bias_q[q], bias_q[q], bias_q[q], bias_q[q] };  // seed with bias
            a = __builtin_amdgcn_mfma_f32_16x16x32_f16(A0, Bf[q][0], a, 0, 0, 0);
            a = __builtin_amdgcn_mfma_f32_16x16x32_f16(A1, Bf[q][1], a, 0, 0, 0);
            a = __builtin_amdgcn_mfma_f32_16x16x32_f16(A2, Bf[q][2], a, 0, 0, 0);
            acc[q] = a;
        }
        __syncthreads();   // all A-reads done before anyone rewrites Hcat

        // elementwise LSTM update: lane has all 4 gates for (batch quad*4+r, j)
        #pragma unroll
        for (int r = 0; r < 4; ++r) {
            const float ig = fsig(acc[0][r]);
            const float fg = fsig(acc[1][r]);
            const float g_ = ftanh(acc[2][r]);
            const float og = fsig(acc[3][r]);
            c_st[r] = fmaf(fg, c_st[r], ig * g_);
            const float hh = og * ftanh(c_st[r]);
            Hcat[quad * 4 + r][D_FC + w * 16 + col] = (_Float16)hh;
        }

        // fc0 for t+1 from prefetched x
        {
            float a = b0c[0], b = b0c[1];
            #pragma unroll
            for (int i = 0; i < IN_F; ++i) {
                a = fmaf(w0c[0][i], xr[i], a);
                b = fmaf(w0c[1][i], xr[i], b);
            }
            h2 p; p.x = (_Float16)a; p.y = (_Float16)b;
            *(h2*)&Hcat[fb][2 * fp] = p;
        }
        // prefetch x(t+2), clamped
        const int tn = (t + 2 < T_STEPS) ? (t + 2) : (T_STEPS - 1);
        #pragma unroll
        for (int i = 0; i < IN_F; ++i) xr[i] = xb[tn * IN_F + i];

        __syncthreads();   // h(t)/h0(t+1) visible before next A-reads
    }

    // ---- output head: out[b] = bo + sum_j h_last[b][j] * Wo[j] ----
    if (tid < MB) {
        float a = bo[0];
        #pragma unroll 8
        for (int j = 0; j < D_H; ++j)
            a = fmaf((float)Hcat[tid][D_FC + j], Wo[j], a);
        out[bblk + tid] = a;
    }
}

extern "C" void kernel_launch(void* const* d_in, const int* in_sizes, int n_in,
                              void* d_out, int out_size, void* d_ws, size_t ws_size,
                              hipStream_t stream) {
    const float* x    = (const float*)d_in[0];
    const float* W0   = (const float*)d_in[1];
    const float* b0   = (const float*)d_in[2];
    const float* W_ih = (const float*)d_in[3];
    const float* W_hh = (const float*)d_in[4];
    const float* b_ih = (const float*)d_in[5];
    const float* b_hh = (const float*)d_in[6];
    const float* Wo   = (const float*)d_in[7];
    const float* bo   = (const float*)d_in[8];
    float* out = (float*)d_out;

    hipLaunchKernelGGL(lstm_mfma, dim3(B_TOT / MB), dim3(256), 0, stream,
                       x, W0, b0, W_ih, W_hh, b_ih, b_hh, Wo, bo, out);
}

// Round 4
// 338.186 us; speedup vs baseline: 4.8893x; 1.0518x over previous
//
#include <hip/hip_runtime.h>

#define B_TOT   4096
#define T_STEPS 512
#define IN_F    5
#define D_FC    32
#define D_H     64
#define MB      8       // batches per block (half M-tile; rows remapped across quads)
#define NROW    16      // MFMA M-tile rows staged in LDS
#define ROWPAD  104     // f16 elems per row (96 + 8 pad; rows stay 16B-aligned)

typedef _Float16 h8 __attribute__((ext_vector_type(8)));
typedef float    f4 __attribute__((ext_vector_type(4)));

__device__ __forceinline__ float fexp2(float x) { return __builtin_amdgcn_exp2f(x); }
__device__ __forceinline__ float frcp(float x)  { return __builtin_amdgcn_rcpf(x); }
__device__ __forceinline__ float fsig(float x) {
    return frcp(1.0f + fexp2(-1.4426950408889634f * x));
}
__device__ __forceinline__ float ftanh(float x) {
    float e = fexp2(2.8853900817779268f * x);   // exp(2x); saturates at +-inf
    return 1.0f - 2.0f * frcp(e + 1.0f);
}

// batch b (0..7) -> M-tile row: quads 0..3 each hold 2 valid rows (regs 0,1)
__device__ __forceinline__ int mrow(int b) { return ((b >> 1) << 2) | (b & 1); }

__global__ __launch_bounds__(256) void lstm_mfma(
    const float* __restrict__ x,
    const float* __restrict__ W0,
    const float* __restrict__ b0,
    const float* __restrict__ W_ih,
    const float* __restrict__ W_hh,
    const float* __restrict__ b_ih,
    const float* __restrict__ b_hh,
    const float* __restrict__ Wo,
    const float* __restrict__ bo,
    float* __restrict__ out)
{
    // double-buffered Hcat: [k 0..31]=h0(t), [32..95]=h(t-1), f16
    __shared__ _Float16 H[2][NROW][ROWPAD];

    const int tid  = threadIdx.x;
    const int lane = tid & 63;
    const int w    = tid >> 6;      // wave id: owns hidden j in [w*16, w*16+16)
    const int col  = lane & 15;
    const int quad = lane >> 4;
    const int bblk = blockIdx.x * MB;

    // ---- resident B-fragments: lane holds gate q for j=w*16+col across K ----
    h8 Bf[4][3];
    #pragma unroll
    for (int q = 0; q < 4; ++q) {
        const int row = q * 64 + w * 16 + col;
        #pragma unroll
        for (int c = 0; c < 3; ++c) {
            h8 f;
            #pragma unroll
            for (int jj = 0; jj < 8; ++jj) {
                const int k = c * 32 + quad * 8 + jj;
                const float wv = (k < D_FC) ? W_ih[row * D_FC + k]
                                            : W_hh[row * D_H + (k - D_FC)];
                f[jj] = (_Float16)wv;
            }
            Bf[q][c] = f;
        }
    }
    float bias_q[4];
    #pragma unroll
    for (int q = 0; q < 4; ++q) {
        const int row = q * 64 + w * 16 + col;
        bias_q[q] = b_ih[row] + b_hh[row];
    }

    // ---- fc0 assignment: thread -> (batch fb, column fc), one output each ----
    const int fb = tid >> 5;        // 0..7
    const int fc = tid & 31;        // 0..31
    const int frow = mrow(fb);
    float w0c[IN_F], b0s;
    #pragma unroll
    for (int i = 0; i < IN_F; ++i) w0c[i] = W0[fc * IN_F + i];
    b0s = b0[fc];

    const float* xb = x + (size_t)(bblk + fb) * T_STEPS * IN_F;

    // ---- init: zero h-regions + garbage rows in BOTH buffers; h0(0) into buf0 ----
    #pragma unroll
    for (int p = 0; p < 2; ++p) {
        H[p][frow][D_FC + fc]      = (_Float16)0.0f;
        H[p][frow][2 * D_FC + fc]  = (_Float16)0.0f;
        const int grow = frow + 2;              // garbage rows {2,3,6,7,10,11,14,15}
        H[p][grow][fc]             = (_Float16)0.0f;
        H[p][grow][D_FC + fc]      = (_Float16)0.0f;
        H[p][grow][2 * D_FC + fc]  = (_Float16)0.0f;
    }
    {
        float a = b0s;
        #pragma unroll
        for (int i = 0; i < IN_F; ++i) a = fmaf(w0c[i], xb[i], a);
        H[0][frow][fc] = (_Float16)a;
    }
    // prefetch x(t=1)
    float xr[IN_F];
    #pragma unroll
    for (int i = 0; i < IN_F; ++i) xr[i] = xb[IN_F + i];

    // cell state: lane holds c for j=w*16+col, batches quad*2 + {0,1}
    float c_st[2] = {0.0f, 0.0f};

    __syncthreads();

    for (int t = 0; t < T_STEPS; ++t) {
        const int rp = t & 1, wp = rp ^ 1;

        // A-fragments (b128, 16B aligned)
        const h8 A0 = *(const h8*)&H[rp][col][quad * 8];
        const h8 A1 = *(const h8*)&H[rp][col][32 + quad * 8];
        const h8 A2 = *(const h8*)&H[rp][col][64 + quad * 8];

        f4 acc[4];
        #pragma unroll
        for (int q = 0; q < 4; ++q) {
            f4 a = { bias_q[q], bias_q[q], bias_q[q], bias_q[q] };
            a = __builtin_amdgcn_mfma_f32_16x16x32_f16(A0, Bf[q][0], a, 0, 0, 0);
            a = __builtin_amdgcn_mfma_f32_16x16x32_f16(A1, Bf[q][1], a, 0, 0, 0);
            a = __builtin_amdgcn_mfma_f32_16x16x32_f16(A2, Bf[q][2], a, 0, 0, 0);
            acc[q] = a;
        }

        // elementwise LSTM: every lane has rows quad*4 + {0,1} valid (2 updates)
        #pragma unroll
        for (int r = 0; r < 2; ++r) {
            const float ig = fsig(acc[0][r]);
            const float fg = fsig(acc[1][r]);
            const float g_ = ftanh(acc[2][r]);
            const float og = fsig(acc[3][r]);
            c_st[r] = fmaf(fg, c_st[r], ig * g_);
            const float hh = og * ftanh(c_st[r]);
            H[wp][quad * 4 + r][D_FC + w * 16 + col] = (_Float16)hh;
        }

        // fc0 for t+1 into write buffer
        {
            float a = b0s;
            #pragma unroll
            for (int i = 0; i < IN_F; ++i) a = fmaf(w0c[i], xr[i], a);
            H[wp][frow][fc] = (_Float16)a;
        }
        // prefetch x(t+2), clamped
        const int tn = (t + 2 < T_STEPS) ? (t + 2) : (T_STEPS - 1);
        #pragma unroll
        for (int i = 0; i < IN_F; ++i) xr[i] = xb[tn * IN_F + i];

        __syncthreads();   // single barrier: writes to buf[wp] visible for next step
    }

    // ---- output head: h_last lives in H[T&1 = 0] ----
    if (tid < MB) {
        const int hr = mrow(tid);
        float a = bo[0];
        #pragma unroll 8
        for (int j = 0; j < D_H; ++j)
            a = fmaf((float)H[0][hr][D_FC + j], Wo[j], a);
        out[bblk + tid] = a;
    }
}

extern "C" void kernel_launch(void* const* d_in, const int* in_sizes, int n_in,
                              void* d_out, int out_size, void* d_ws, size_t ws_size,
                              hipStream_t stream) {
    const float* x    = (const float*)d_in[0];
    const float* W0   = (const float*)d_in[1];
    const float* b0   = (const float*)d_in[2];
    const float* W_ih = (const float*)d_in[3];
    const float* W_hh = (const float*)d_in[4];
    const float* b_ih = (const float*)d_in[5];
    const float* b_hh = (const float*)d_in[6];
    const float* Wo   = (const float*)d_in[7];
    const float* bo   = (const float*)d_in[8];
    float* out = (float*)d_out;

    hipLaunchKernelGGL(lstm_mfma, dim3(B_TOT / MB), dim3(256), 0, stream,
                       x, W0, b0, W_ih, W_hh, b_ih, b_hh, Wo, bo, out);
}